// Round 5
// baseline (263.468 us; speedup 1.0000x reference)
//
#include <hip/hip_runtime.h>
#include <stdint.h>

typedef __bf16 bf16x8 __attribute__((ext_vector_type(8)));
typedef float floatx16 __attribute__((ext_vector_type(16)));
typedef uint32_t uint32x4 __attribute__((ext_vector_type(4)));

#define GRID_W   15
#define PAD_W    17
#define CELLS    221            // 13*17 padded cells
#define NHEX     165
#define OUTC     64
#define KDIM     448
#define CWORDS   32             // uint32 words per cell (64 bf16)
#define SXW      (CELLS * CWORDS)   // 7072 words = 28288 B per buffer
#define NSAMP    4              // samples per block

// round-to-nearest-even fp32 -> bf16, packed pair
__device__ __forceinline__ uint32_t pack2bf(float a, float b) {
    union { float f; uint32_t u; } ua, ub;
    ua.f = a; ub.f = b;
    uint32_t ra = (ua.u + 0x7fffu + ((ua.u >> 16) & 1u)) >> 16;
    uint32_t rb = (ub.u + 0x7fffu + ((ub.u >> 16) & 1u)) >> 16;
    return ra | (rb << 16);
}

// ---- prep: W fp32 -> bf16 (64*448 elems = 7168 float4s, 28 blocks x 256) ----
__global__ void wprep_kernel(const float* __restrict__ W, uint32_t* __restrict__ Wbf) {
    int i = blockIdx.x * 256 + threadIdx.x;
    float4 v = ((const float4*)W)[i];
    uint2 p; p.x = pack2bf(v.x, v.y); p.y = pack2bf(v.z, v.w);
    ((uint2*)Wbf)[i] = p;
}

__global__ __launch_bounds__(256, 2)
void hexconv_kernel(const float* __restrict__ x,
                    const uint32_t* __restrict__ Wbf,
                    const float* __restrict__ bias,
                    float* __restrict__ out, int B)
{
    __shared__ __align__(16) uint32_t sx[2][SXW];   // 56,576 B double-buffered grid

    const int tid  = threadIdx.x;
    const int lane = tid & 63;
    const int wave = tid >> 6;    // 4 waves
    const int ln31 = lane & 31;   // A-row m / B-col n / C-col
    const int h    = lane >> 5;   // k-half within fragment
    const int ow   = wave & 1;    // o-group: channels [ow*32, ow*32+32)
    const int mw   = wave >> 1;   // m-parity: tiles mw, mw+2, mw+4

    // ---- B fragments for full K: 28 k-steps x 16B, 112 VGPRs (once per block) ----
    const int o = ow * 32 + ln31;
    uint32x4 bw[28];
    {
        const uint32_t* wp = Wbf + o * (KDIM / 2) + h * 4;   // 224 words per o-row
        #pragma unroll
        for (int ks = 0; ks < 28; ++ks)
            bw[ks] = *(const uint32x4*)(wp + ks * 8);
    }
    const float bias_o = bias[o];

    // ---- zero both buffers once (halo cells stay 0 for all samples) ----
    for (int i = tid; i < 2 * SXW / 4; i += 256)
        ((uint32x4*)sx)[i] = (uint32x4){0u, 0u, 0u, 0u};
    __syncthreads();

    const int b0 = blockIdx.x * NSAMP;

    // stage one sample: fp32 global -> bf16 swizzled LDS grid
    auto stage = [&](int b, uint32_t* buf) {
        const float4* xs = (const float4*)(x + (size_t)b * NHEX * 64);
        #pragma unroll 1
        for (int i = tid; i < NHEX * 16; i += 256) {   // 2640 float4s
            int n = i >> 4, d = i & 15;
            float4 v = xs[i];
            int y0 = n / GRID_W, x0 = n - y0 * GRID_W;
            int cell = (y0 + 1) * PAD_W + (x0 + 1);
            int pc   = (d >> 1) ^ (cell & 7);
            uint2 p; p.x = pack2bf(v.x, v.y); p.y = pack2bf(v.z, v.w);
            *(uint2*)(buf + cell * CWORDS + pc * 4 + (d & 1) * 2) = p;
        }
    };

    // neighbor cells for this lane's hex row in tile mt
    auto calc_cells = [&](int mt, int* cells) {
        int n = mt * 32 + ln31;
        bool valid = (n < NHEX);
        int nn = valid ? n : 0;
        int y0 = nn / GRID_W, x0 = nn - y0 * GRID_W;
        int base = (y0 + 1) * PAD_W + (x0 + 1);
        bool use0 = (y0 & 1);
        const int off0[7] = {-17, -16, -1, 0, 1, 17, 18};
        const int off1[7] = {-18, -17, -1, 0, 1, 16, 17};
        #pragma unroll
        for (int j = 0; j < 7; ++j)
            cells[j] = valid ? (base + (use0 ? off0[j] : off1[j])) : 16; // cell 16 = halo
    };

    if (b0 < B) stage(b0, sx[0]);
    __syncthreads();

    #pragma unroll 1
    for (int s = 0; s < NSAMP; ++s) {
        int b = b0 + s;
        const uint32_t* cur = sx[s & 1];
        if (s + 1 < NSAMP && b + 1 < B) stage(b + 1, sx[(s + 1) & 1]);

        if (b < B) {
            int cA[7], cB[7], cC[7];
            calc_cells(mw,     cA);
            calc_cells(mw + 2, cB);
            calc_cells(mw + 4, cC);

            floatx16 aA = {0,0,0,0,0,0,0,0,0,0,0,0,0,0,0,0};
            floatx16 aB = {0,0,0,0,0,0,0,0,0,0,0,0,0,0,0,0};
            floatx16 aC = {0,0,0,0,0,0,0,0,0,0,0,0,0,0,0,0};

            #pragma unroll
            for (int ks = 0; ks < 28; ++ks) {
                const int j  = ks >> 2;          // neighbor index (16 | 64 -> uniform)
                const int lc = (ks & 3) * 2 + h; // logical 16B chunk within cell
                int eA = cA[j], eB = cB[j], eC = cC[j];
                uint32x4 vA = *(const uint32x4*)(cur + eA * CWORDS + (lc ^ (eA & 7)) * 4);
                uint32x4 vB = *(const uint32x4*)(cur + eB * CWORDS + (lc ^ (eB & 7)) * 4);
                uint32x4 vC = *(const uint32x4*)(cur + eC * CWORDS + (lc ^ (eC & 7)) * 4);
                aA = __builtin_amdgcn_mfma_f32_32x32x16_bf16(
                         __builtin_bit_cast(bf16x8, vA),
                         __builtin_bit_cast(bf16x8, bw[ks]), aA, 0, 0, 0);
                aB = __builtin_amdgcn_mfma_f32_32x32x16_bf16(
                         __builtin_bit_cast(bf16x8, vB),
                         __builtin_bit_cast(bf16x8, bw[ks]), aB, 0, 0, 0);
                aC = __builtin_amdgcn_mfma_f32_32x32x16_bf16(
                         __builtin_bit_cast(bf16x8, vC),
                         __builtin_bit_cast(bf16x8, bw[ks]), aC, 0, 0, 0);
            }

            // C/D: col = lane&31 (= o), row = (r&3) + 8*(r>>2) + 4*h
            float* outb = out + (size_t)b * NHEX * OUTC;
            #pragma unroll
            for (int r = 0; r < 16; ++r) {
                int row = (r & 3) + 8 * (r >> 2) + 4 * h;
                int nA = mw * 32 + row;
                int nB = (mw + 2) * 32 + row;
                int nC = (mw + 4) * 32 + row;
                outb[(size_t)nA * OUTC + o] = aA[r] + bias_o;            // rows < 128: valid
                outb[(size_t)nB * OUTC + o] = aB[r] + bias_o;            // rows < 160: valid
                if (nC < NHEX) outb[(size_t)nC * OUTC + o] = aC[r] + bias_o;
            }
        }
        __syncthreads();
    }
}

extern "C" void kernel_launch(void* const* d_in, const int* in_sizes, int n_in,
                              void* d_out, int out_size, void* d_ws, size_t ws_size,
                              hipStream_t stream) {
    const float* x    = (const float*)d_in[0];
    const float* W    = (const float*)d_in[1];
    const float* bias = (const float*)d_in[2];
    float* out        = (float*)d_out;
    uint32_t* Wbf     = (uint32_t*)d_ws;      // 57,344 B of bf16 W

    wprep_kernel<<<28, 256, 0, stream>>>(W, Wbf);

    int B = in_sizes[0] / (NHEX * 64);
    int grid = (B + NSAMP - 1) / NSAMP;
    hexconv_kernel<<<grid, 256, 0, stream>>>(x, Wbf, bias, out, B);
}